// Round 1
// baseline (5308.825 us; speedup 1.0000x reference)
//
#include <hip/hip_runtime.h>

#define T_STEPS 2048
#define BATCH   2048
#define HIDN    128

typedef short v8s __attribute__((ext_vector_type(8)));
typedef float v4f __attribute__((ext_vector_type(4)));
typedef unsigned short u16;
typedef unsigned int   u32;

// ---------------- LDS layout (bytes) ----------------
// W1 image: 32 tiles x 4 kt x 1KB b-frag chunks   [0, 131072)
// h1 dbuf:  2 x 4KB fragment-order images         [131072, 139264)
// h2 dbuf:  2 x 4KB fragment-order images         [139264, 147456)
#define LDS_W1    0
#define LDS_H1    131072
#define LDS_H2    (131072 + 8192)
#define LDS_TOTAL (131072 + 16384)

__device__ __forceinline__ u16 f2bf(float x) {
    u32 u = __float_as_uint(x);
    u32 r = (u + 0x7FFFu + ((u >> 16) & 1u)) >> 16;
    return (u16)r;
}
__device__ __forceinline__ float rcpf(float x) { return __builtin_amdgcn_rcpf(x); }
__device__ __forceinline__ float sigf(float x) { return rcpf(1.0f + __expf(-x)); }
__device__ __forceinline__ float tanhf_(float x) {
    float e = __expf(2.0f * x);
    return 1.0f - 2.0f * rcpf(e + 1.0f);
}
// byte offset of element (row r, k) inside a 4KB fragment-order image
__device__ __forceinline__ int fragoff(int r, int k) {
    return ((k >> 5) << 10) + ((((k >> 3) & 3) * 16 + r) << 4) + ((k & 7) << 1);
}

#define MFMA_BF16 __builtin_amdgcn_mfma_f32_16x16x32_bf16

// ---- layer 2 for step s-1: A = [h1[s-1] | h2[s-2]], plus wave-7 out tile ----
#define L2_COMPUTE()                                                             \
    if (s >= 1) {                                                                \
        v8s a2[4];                                                               \
        _Pragma("unroll")                                                        \
        for (int kt = 0; kt < 4; ++kt)                                           \
            a2[kt] = *(const v8s*)(h2r + (kt << 10) + l * 16);                   \
        __builtin_amdgcn_s_setprio(1);                                           \
        _Pragma("unroll")                                                        \
        for (int tl = 0; tl < 4; ++tl) {                                         \
            v4f a = {0.f, 0.f, 0.f, 0.f};                                        \
            _Pragma("unroll")                                                    \
            for (int kt = 0; kt < 4; ++kt)                                       \
                a = MFMA_BF16(a1[kt], w2[tl][kt], a, 0, 0, 0);                   \
            _Pragma("unroll")                                                    \
            for (int kt = 0; kt < 4; ++kt)                                       \
                a = MFMA_BF16(a2[kt], w2[tl][kt + 4], a, 0, 0, 0);               \
            accL2[tl] = a;                                                       \
        }                                                                        \
        __builtin_amdgcn_s_setprio(0);                                           \
        if (w == 7 && s >= 2) {                                                  \
            v4f oa = {0.f, 0.f, 0.f, 0.f};                                       \
            _Pragma("unroll")                                                    \
            for (int kt = 0; kt < 4; ++kt)                                       \
                oa = MFMA_BF16(a2[kt], wlin[kt], oa, 0, 0, 0);                   \
            if (low && u < 4) {                                                  \
                _Pragma("unroll")                                                \
                for (int d = 0; d < 4; ++d)                                      \
                    out[((long)(s - 2) * BATCH + b0 + 4 * q + d) * 4 + u] =      \
                        oa[d] + blin;                                            \
            }                                                                    \
        }                                                                        \
    }

// ---- layer-2 activation (low lanes: q<2), writes h2[s-1] ----
#define L2_ACT()                                                                 \
    if (s >= 1 && low) {                                                         \
        char* hw = (char*)smem + LDS_H2 + ((s - 1) & 1) * 4096;                  \
        _Pragma("unroll")                                                        \
        for (int d = 0; d < 4; ++d) {                                            \
            float gI = accL2[0][d] + bg[0];                                      \
            float gF = accL2[1][d] + bg[1];                                      \
            float gG = accL2[2][d] + bg[2];                                      \
            float gO = accL2[3][d] + bg[3];                                      \
            float si = sigf(gI), sf = sigf(gF), tg = tanhf_(gG), so = sigf(gO);  \
            c[d] = sf * c[d] + si * tg;                                          \
            float h = so * tanhf_(c[d]);                                         \
            *(u16*)(hw + cb + ((4 * q + d) << 4)) = f2bf(h);                     \
        }                                                                        \
    }

// ---- layer 1 for step s: A = [h1[s-1] | x[s] in rows 8..15] ----
#define L1_COMPUTE()                                                             \
    if (s < T_STEPS) {                                                           \
        v8s ax = {0, 0, 0, 0, 0, 0, 0, 0};                                       \
        if (q == 0 && u >= 8) {                                                  \
            ax[0] = (short)f2bf(xcur.x); ax[1] = (short)f2bf(xcur.y);            \
            ax[2] = (short)f2bf(xcur.z); ax[3] = (short)f2bf(xcur.w);            \
        }                                                                        \
        __builtin_amdgcn_s_setprio(1);                                           \
        _Pragma("unroll")                                                        \
        for (int tl = 0; tl < 4; ++tl) {                                         \
            v4f a = {0.f, 0.f, 0.f, 0.f};                                        \
            _Pragma("unroll")                                                    \
            for (int kt = 0; kt < 4; ++kt) {                                     \
                v8s wf = *(const v8s*)(smem + LDS_W1 +                           \
                          (((w * 4 + tl) * 4 + kt) << 10) + l * 16);             \
                a = MFMA_BF16(a1[kt], wf, a, 0, 0, 0);                           \
            }                                                                    \
            a = MFMA_BF16(ax, wx[tl], a, 0, 0, 0);                               \
            accL1[tl] = a;                                                       \
        }                                                                        \
        __builtin_amdgcn_s_setprio(0);                                           \
    }

// ---- layer-1 activation (high lanes: q>=2), writes h1[s] rows m and m+8 ----
#define L1_ACT()                                                                 \
    if (s < T_STEPS && !low) {                                                   \
        char* hw = (char*)smem + LDS_H1 + (s & 1) * 4096;                        \
        _Pragma("unroll")                                                        \
        for (int d = 0; d < 4; ++d) {                                            \
            float gI = accL1[0][d] + bg[0];                                      \
            float gF = accL1[1][d] + bg[1];                                      \
            float gG = accL1[2][d] + bg[2];                                      \
            float gO = accL1[3][d] + bg[3];                                      \
            float si = sigf(gI), sf = sigf(gF), tg = tanhf_(gG), so = sigf(gO);  \
            c[d] = sf * c[d] + si * tg;                                          \
            float h = so * tanhf_(c[d]);                                         \
            u16 hb = f2bf(h);                                                    \
            int r = 4 * (q - 2) + d;                                             \
            *(u16*)(hw + cb + (r << 4)) = hb;                                    \
            *(u16*)(hw + cb + (r << 4) + 128) = hb;                              \
        }                                                                        \
    }

__global__ __launch_bounds__(512, 2) void lstm_seq_kernel(
    const float* __restrict__ input,
    const float* __restrict__ W_ih1, const float* __restrict__ W_hh1,
    const float* __restrict__ b_ih1, const float* __restrict__ b_hh1,
    const float* __restrict__ W_ih2, const float* __restrict__ W_hh2,
    const float* __restrict__ b_ih2, const float* __restrict__ b_hh2,
    const float* __restrict__ W_lin, const float* __restrict__ b_lin,
    const float* __restrict__ h0,  const float* __restrict__ c0,
    const float* __restrict__ h02, const float* __restrict__ c02,
    float* __restrict__ out)
{
    extern __shared__ char smem[];
    const int tid = threadIdx.x;
    const int w   = tid >> 6;     // wave 0..7
    const int l   = tid & 63;
    const int u   = l & 15;       // MFMA row/col index
    const int q   = l >> 4;       // MFMA quad
    const int b0  = blockIdx.x * 8;
    const bool low = (q < 2);     // q<2: layer-2 cells; q>=2: layer-1 cells
    const int j   = w * 16 + u;   // hidden unit owned by this lane

    // ---------------- init: zero h bufs (16KB) ----------------
    for (int e = tid; e < 4096; e += 512)
        ((float*)(smem + LDS_H1))[e] = 0.0f;
    __syncthreads();
    // preload h0 -> h1buf[1] (rows m and m+8), h02 -> h2buf[1] (rows m)
    for (int e = tid; e < 1024; e += 512) {
        int m = e >> 7, jj = e & 127;
        u16 hv1 = f2bf(h0 [(b0 + m) * HIDN + jj]);
        u16 hv2 = f2bf(h02[(b0 + m) * HIDN + jj]);
        int fo = fragoff(m, jj);
        *(u16*)(smem + LDS_H1 + 4096 + fo)       = hv1;
        *(u16*)(smem + LDS_H1 + 4096 + fo + 128) = hv1;   // row m+8 dup
        *(u16*)(smem + LDS_H2 + 4096 + fo)       = hv2;
    }

    // ---------------- W1 b-frag image in LDS ----------------
    #pragma unroll
    for (int tl = 0; tl < 4; ++tl) {
        int r = tl * 128 + j;
        #pragma unroll
        for (int kt = 0; kt < 4; ++kt) {
            const float* src = W_hh1 + r * HIDN + kt * 32 + q * 8;
            v8s f;
            #pragma unroll
            for (int b = 0; b < 8; ++b) f[b] = (short)f2bf(src[b]);
            *(v8s*)(smem + LDS_W1 + (((w * 4 + tl) * 4 + kt) << 10) + l * 16) = f;
        }
    }

    // ---------------- resident register fragments ----------------
    // layer-2 weights: kt 0..3 = W_ih2 (A=h1_new), kt 4..7 = W_hh2 (A=h2_old)
    v8s w2[4][8];
    #pragma unroll
    for (int tl = 0; tl < 4; ++tl) {
        int r = tl * 128 + j;
        #pragma unroll
        for (int kt = 0; kt < 8; ++kt) {
            const float* src = (kt < 4) ? (W_ih2 + r * HIDN + kt * 32 + q * 8)
                                        : (W_hh2 + r * HIDN + (kt - 4) * 32 + q * 8);
            v8s f;
            #pragma unroll
            for (int b = 0; b < 8; ++b) f[b] = (short)f2bf(src[b]);
            w2[tl][kt] = f;
        }
    }
    // x-tile weights (K slots 0..3 of a 32-wide tile)
    v8s wx[4];
    #pragma unroll
    for (int tl = 0; tl < 4; ++tl) {
        int r = tl * 128 + j;
        v8s f;
        #pragma unroll
        for (int b = 0; b < 8; ++b) {
            int k = q * 8 + b;
            f[b] = (k < 4) ? (short)f2bf(W_ih1[r * 4 + k]) : (short)0;
        }
        wx[tl] = f;
    }
    // W_lin b-frags (wave 7 only; cols u<4 valid)
    v8s wlin[4];
    if (w == 7) {
        #pragma unroll
        for (int kt = 0; kt < 4; ++kt) {
            v8s f;
            #pragma unroll
            for (int b = 0; b < 8; ++b) {
                int kk = kt * 32 + q * 8 + b;
                f[b] = (u < 4) ? (short)f2bf(W_lin[u * HIDN + kk]) : (short)0;
            }
            wlin[kt] = f;
        }
    }

    // biases + c-state, selected per lane half
    float bg[4];
    #pragma unroll
    for (int g = 0; g < 4; ++g)
        bg[g] = low ? (b_ih2[g * 128 + j] + b_hh2[g * 128 + j])
                    : (b_ih1[g * 128 + j] + b_hh1[g * 128 + j]);
    float blin = (w == 7 && u < 4) ? b_lin[u] : 0.0f;
    float c[4];
    #pragma unroll
    for (int d = 0; d < 4; ++d) {
        int m = low ? (4 * q + d) : (4 * (q - 2) + d);
        c[d] = low ? c02[(b0 + m) * HIDN + j] : c0[(b0 + m) * HIDN + j];
    }
    // x[0] preload (lanes q==0, u>=8 hold batch row u-8)
    float4 xcur = {0, 0, 0, 0}, xnext = {0, 0, 0, 0};
    if (q == 0 && u >= 8)
        xcur = *(const float4*)(input + (long)(b0 + u - 8) * 4);

    const int cb = fragoff(0, j);   // lane-const column part of h-write address
    __syncthreads();

    // ------- pipelined time loop: slot s does l1(s) and l2(s-1) -------
    // Wave-group stagger: waves 4..7 (incl. wave 7's out tile + store) run
    // L2-first, waves 0..3 run L1-first.  SIMD pairs are (w, w+4), so each
    // SIMD hosts one wave in an MFMA phase while the other is in a VALU/LDS
    // phase.  Activation is split per layer (no accL1/accL2 cndmask coupling)
    // so act-VALU can issue in the shadow of the other layer's MFMA stream.
    for (int s = 0; s <= T_STEPS; ++s) {
        const char* h1r = smem + LDS_H1 + ((s - 1) & 1) * 4096;  // h1[s-1]
        const char* h2r = smem + LDS_H2 + (s & 1) * 4096;        // h2[s-2]

        // x prefetch for slot s+1 issued at slot top: full slot of HBM cover,
        // barrier's vmcnt drain becomes free.
        if (q == 0 && u >= 8 && s + 1 < T_STEPS)
            xnext = *(const float4*)(input + ((long)(s + 1) * BATCH + b0 + u - 8) * 4);

        v8s a1[4];
        #pragma unroll
        for (int kt = 0; kt < 4; ++kt)
            a1[kt] = *(const v8s*)(h1r + (kt << 10) + l * 16);

        v4f accL1[4], accL2[4];
        if (w >= 4) {
            L2_COMPUTE();
            L2_ACT();
            L1_COMPUTE();
            L1_ACT();
        } else {
            L1_COMPUTE();
            L1_ACT();
            L2_COMPUTE();
            L2_ACT();
        }

        xcur = xnext;
        __syncthreads();
    }

    // epilogue: out[T-1] from h2[T-1] (written in slot T, visible after barrier)
    if (w == 7) {
        const char* h2r = smem + LDS_H2 + ((T_STEPS - 1) & 1) * 4096;
        v4f oa = {0.f, 0.f, 0.f, 0.f};
        #pragma unroll
        for (int kt = 0; kt < 4; ++kt) {
            v8s a = *(const v8s*)(h2r + (kt << 10) + l * 16);
            oa = MFMA_BF16(a, wlin[kt], oa, 0, 0, 0);
        }
        if (low && u < 4) {
            #pragma unroll
            for (int d = 0; d < 4; ++d)
                out[((long)(T_STEPS - 1) * BATCH + b0 + 4 * q + d) * 4 + u] = oa[d] + blin;
        }
    }
}

extern "C" void kernel_launch(void* const* d_in, const int* in_sizes, int n_in,
                              void* d_out, int out_size, void* d_ws, size_t ws_size,
                              hipStream_t stream) {
    const float* input = (const float*)d_in[0];
    // d_in[1] = future (unused, ==0)
    const float* W_ih1 = (const float*)d_in[2];
    const float* W_hh1 = (const float*)d_in[3];
    const float* b_ih1 = (const float*)d_in[4];
    const float* b_hh1 = (const float*)d_in[5];
    const float* W_ih2 = (const float*)d_in[6];
    const float* W_hh2 = (const float*)d_in[7];
    const float* b_ih2 = (const float*)d_in[8];
    const float* b_hh2 = (const float*)d_in[9];
    const float* W_lin = (const float*)d_in[10];
    const float* b_lin = (const float*)d_in[11];
    const float* h0    = (const float*)d_in[12];
    const float* c0    = (const float*)d_in[13];
    const float* h02   = (const float*)d_in[14];
    const float* c02   = (const float*)d_in[15];
    float* out = (float*)d_out;

    (void)hipFuncSetAttribute((const void*)lstm_seq_kernel,
                              hipFuncAttributeMaxDynamicSharedMemorySize, LDS_TOTAL);
    lstm_seq_kernel<<<BATCH / 8, 512, LDS_TOTAL, stream>>>(
        input, W_ih1, W_hh1, b_ih1, b_hh1, W_ih2, W_hh2, b_ih2, b_hh2,
        W_lin, b_lin, h0, c0, h02, c02, out);
}

// Round 2
// 4211.998 us; speedup vs baseline: 1.2604x; 1.2604x over previous
//
#include <hip/hip_runtime.h>

#define T_STEPS 2048
#define BATCH   2048
#define HIDN    128

typedef short v8s __attribute__((ext_vector_type(8)));
typedef float v4f __attribute__((ext_vector_type(4)));
typedef unsigned short u16;
typedef unsigned int   u32;

// ---------------- LDS layout (bytes) ----------------
// W1 image: 32 tiles x 4 kt x 1KB b-frag chunks   [0, 131072)
// h1 dbuf:  2 x 4KB fragment-order images         [131072, 139264)
// h2 dbuf:  2 x 4KB fragment-order images         [139264, 147456)
#define LDS_W1    0
#define LDS_H1    131072
#define LDS_H2    (131072 + 8192)
#define LDS_TOTAL (131072 + 16384)

__device__ __forceinline__ u16 f2bf(float x) {
    u32 u = __float_as_uint(x);
    u32 r = (u + 0x7FFFu + ((u >> 16) & 1u)) >> 16;
    return (u16)r;
}
__device__ __forceinline__ float rcpf(float x) { return __builtin_amdgcn_rcpf(x); }
__device__ __forceinline__ float sigf(float x) { return rcpf(1.0f + __expf(-x)); }
__device__ __forceinline__ float tanhf_(float x) {
    float e = __expf(2.0f * x);
    return 1.0f - 2.0f * rcpf(e + 1.0f);
}
// byte offset of element (row r, k) inside a 4KB fragment-order image
__device__ __forceinline__ int fragoff(int r, int k) {
    return ((k >> 5) << 10) + ((((k >> 3) & 3) * 16 + r) << 4) + ((k & 7) << 1);
}

#define MFMA_BF16 __builtin_amdgcn_mfma_f32_16x16x32_bf16

__global__ __launch_bounds__(512, 2) void lstm_seq_kernel(
    const float* __restrict__ input,
    const float* __restrict__ W_ih1, const float* __restrict__ W_hh1,
    const float* __restrict__ b_ih1, const float* __restrict__ b_hh1,
    const float* __restrict__ W_ih2, const float* __restrict__ W_hh2,
    const float* __restrict__ b_ih2, const float* __restrict__ b_hh2,
    const float* __restrict__ W_lin, const float* __restrict__ b_lin,
    const float* __restrict__ h0,  const float* __restrict__ c0,
    const float* __restrict__ h02, const float* __restrict__ c02,
    float* __restrict__ out)
{
    extern __shared__ char smem[];
    const int tid = threadIdx.x;
    const int w   = tid >> 6;     // wave 0..7
    const int l   = tid & 63;
    const int u   = l & 15;       // MFMA row/col index
    const int q   = l >> 4;       // MFMA quad
    const int b0  = blockIdx.x * 8;
    const bool low = (q < 2);
    const int j   = w * 16 + u;   // hidden unit owned by this lane
    // batch-pair base owned by this lane (both layers): q0->{0,1} q1->{4,5} q2->{2,3} q3->{6,7}
    const int m0  = ((q & 1) << 2) | ((q >> 1) << 1);

    // ---------------- init: zero h bufs (16KB) ----------------
    for (int e = tid; e < 4096; e += 512)
        ((float*)(smem + LDS_H1))[e] = 0.0f;
    __syncthreads();
    // preload h0 -> h1buf[1] (rows m and m+8), h02 -> h2buf[1] (rows m)
    for (int e = tid; e < 1024; e += 512) {
        int m = e >> 7, jj = e & 127;
        u16 hv1 = f2bf(h0 [(b0 + m) * HIDN + jj]);
        u16 hv2 = f2bf(h02[(b0 + m) * HIDN + jj]);
        int fo = fragoff(m, jj);
        *(u16*)(smem + LDS_H1 + 4096 + fo)       = hv1;
        *(u16*)(smem + LDS_H1 + 4096 + fo + 128) = hv1;   // row m+8 dup
        *(u16*)(smem + LDS_H2 + 4096 + fo)       = hv2;
    }

    // ---------------- W1 b-frag image in LDS ----------------
    #pragma unroll
    for (int tl = 0; tl < 4; ++tl) {
        int r = tl * 128 + j;
        #pragma unroll
        for (int kt = 0; kt < 4; ++kt) {
            const float* src = W_hh1 + r * HIDN + kt * 32 + q * 8;
            v8s f;
            #pragma unroll
            for (int b = 0; b < 8; ++b) f[b] = (short)f2bf(src[b]);
            *(v8s*)(smem + LDS_W1 + (((w * 4 + tl) * 4 + kt) << 10) + l * 16) = f;
        }
    }

    // ---------------- resident register fragments ----------------
    // layer-2 weights: kt 0..3 = W_ih2 (A=h1_new), kt 4..7 = W_hh2 (A=h2_old)
    v8s w2[4][8];
    #pragma unroll
    for (int tl = 0; tl < 4; ++tl) {
        int r = tl * 128 + j;
        #pragma unroll
        for (int kt = 0; kt < 8; ++kt) {
            const float* src = (kt < 4) ? (W_ih2 + r * HIDN + kt * 32 + q * 8)
                                        : (W_hh2 + r * HIDN + (kt - 4) * 32 + q * 8);
            v8s f;
            #pragma unroll
            for (int b = 0; b < 8; ++b) f[b] = (short)f2bf(src[b]);
            w2[tl][kt] = f;
        }
    }
    // x-tile weights (K slots 0..3 of a 32-wide tile)
    v8s wx[4];
    #pragma unroll
    for (int tl = 0; tl < 4; ++tl) {
        int r = tl * 128 + j;
        v8s f;
        #pragma unroll
        for (int b = 0; b < 8; ++b) {
            int k = q * 8 + b;
            f[b] = (k < 4) ? (short)f2bf(W_ih1[r * 4 + k]) : (short)0;
        }
        wx[tl] = f;
    }
    // W_lin b-frags (wave 7 only; cols u<4 valid)
    v8s wlin[4];
    if (w == 7) {
        #pragma unroll
        for (int kt = 0; kt < 4; ++kt) {
            v8s f;
            #pragma unroll
            for (int b = 0; b < 8; ++b) {
                int kk = kt * 32 + q * 8 + b;
                f[b] = (u < 4) ? (short)f2bf(W_lin[u * HIDN + kk]) : (short)0;
            }
            wlin[kt] = f;
        }
    }

    // biases (both layers, all lanes; column-only dependence)
    float b1g[4], b2g[4];
    #pragma unroll
    for (int g = 0; g < 4; ++g) {
        b1g[g] = b_ih1[g * 128 + j] + b_hh1[g * 128 + j];
        b2g[g] = b_ih2[g * 128 + j] + b_hh2[g * 128 + j];
    }
    float blin = (w == 7 && u < 4) ? b_lin[u] : 0.0f;

    // c-state: c[0..1] = layer-2 cells (batch m0, m0+1); c[2..3] = layer-1 cells
    float c[4];
    c[0] = c02[(b0 + m0)     * HIDN + j];
    c[1] = c02[(b0 + m0 + 1) * HIDN + j];
    c[2] = c0 [(b0 + m0)     * HIDN + j];
    c[3] = c0 [(b0 + m0 + 1) * HIDN + j];

    // x[0] preload (lanes q==0, u>=8 hold batch row u-8)
    float4 xcur = {0, 0, 0, 0}, xnext = {0, 0, 0, 0};
    if (q == 0 && u >= 8)
        xcur = *(const float4*)(input + (long)(b0 + u - 8) * 4);

    const int cb = fragoff(0, j);   // lane-const column part of h-write address
    __syncthreads();

    // ---------------- pipelined time loop: slot s does l1(s) and l2(s-1) ----
    for (int s = 0; s <= T_STEPS; ++s) {
        const char* h1r = smem + LDS_H1 + ((s - 1) & 1) * 4096;  // h1[s-1]
        const char* h2r = smem + LDS_H2 + (s & 1) * 4096;        // h2[s-2]

        // x prefetch for slot s+1 at slot TOP: ~full slot of HBM-latency cover
        if (q == 0 && u >= 8 && s + 1 < T_STEPS)
            xnext = *(const float4*)(input + ((long)(s + 1) * BATCH + b0 + u - 8) * 4);

        v8s a1[4];
        #pragma unroll
        for (int kt = 0; kt < 4; ++kt)
            a1[kt] = *(const v8s*)(h1r + (kt << 10) + l * 16);

        // ---- layer 2 for step s-1: A = [h1[s-1] | h2[s-2]] ----
        v4f accL2[4];
        if (s >= 1) {
            v8s a2[4];
            #pragma unroll
            for (int kt = 0; kt < 4; ++kt)
                a2[kt] = *(const v8s*)(h2r + (kt << 10) + l * 16);
            #pragma unroll
            for (int tl = 0; tl < 4; ++tl) {
                v4f a = {b2g[tl], b2g[tl], b2g[tl], b2g[tl]};  // bias-init C
                #pragma unroll
                for (int kt = 0; kt < 4; ++kt)
                    a = MFMA_BF16(a1[kt], w2[tl][kt], a, 0, 0, 0);
                #pragma unroll
                for (int kt = 0; kt < 4; ++kt)
                    a = MFMA_BF16(a2[kt], w2[tl][kt + 4], a, 0, 0, 0);
                accL2[tl] = a;
            }
            // out[s-2] = h2[s-2] @ W_lin^T (wave 7 extra tile, same A frags)
            if (w == 7 && s >= 2) {
                v4f oa = {0.f, 0.f, 0.f, 0.f};
                #pragma unroll
                for (int kt = 0; kt < 4; ++kt)
                    oa = MFMA_BF16(a2[kt], wlin[kt], oa, 0, 0, 0);
                if (low && u < 4) {
                    #pragma unroll
                    for (int d = 0; d < 4; ++d)
                        out[((long)(s - 2) * BATCH + b0 + 4 * q + d) * 4 + u] = oa[d] + blin;
                }
            }
        }

        // ---- actL2: full-lane, 2 elements/lane (shfl redistributes rows) ----
        // Placed BEFORE the L1 MFMA burst; depends only on accL2 -> overlaps L1 MFMAs.
        if (s >= 1) {
            float e0[4], e1[4];
            #pragma unroll
            for (int g = 0; g < 4; ++g) {
                float s2 = __shfl_xor(accL2[g][2], 32, 64);
                float s3 = __shfl_xor(accL2[g][3], 32, 64);
                e0[g] = low ? accL2[g][0] : s2;   // high lanes take partner rows 4q'+2..3
                e1[g] = low ? accL2[g][1] : s3;
            }
            char* hw = (char*)smem + LDS_H2 + ((s - 1) & 1) * 4096;
            #pragma unroll
            for (int e = 0; e < 2; ++e) {
                float gI = e ? e1[0] : e0[0];
                float gF = e ? e1[1] : e0[1];
                float gG = e ? e1[2] : e0[2];
                float gO = e ? e1[3] : e0[3];
                float si = sigf(gI), sf = sigf(gF), tg = tanhf_(gG), so = sigf(gO);
                c[e] = sf * c[e] + si * tg;
                float h = so * tanhf_(c[e]);
                *(u16*)(hw + cb + ((m0 + e) << 4)) = f2bf(h);
            }
        }

        // ---- layer 1 for step s: A = [h1[s-1] | x[s] in rows 8..15] ----
        v4f accL1[4];
        if (s < T_STEPS) {
            v8s ax = {0, 0, 0, 0, 0, 0, 0, 0};
            if (q == 0 && u >= 8) {
                ax[0] = (short)f2bf(xcur.x); ax[1] = (short)f2bf(xcur.y);
                ax[2] = (short)f2bf(xcur.z); ax[3] = (short)f2bf(xcur.w);
            }
            #pragma unroll
            for (int tl = 0; tl < 4; ++tl) {
                v4f a = {b1g[tl], b1g[tl], b1g[tl], b1g[tl]};  // bias-init C
                #pragma unroll
                for (int kt = 0; kt < 4; ++kt) {
                    v8s wf = *(const v8s*)(smem + LDS_W1 +
                              (((w * 4 + tl) * 4 + kt) << 10) + l * 16);
                    a = MFMA_BF16(a1[kt], wf, a, 0, 0, 0);
                }
                a = MFMA_BF16(ax, wx[tl], a, 0, 0, 0);
                accL1[tl] = a;
            }
        }

        // ---- actL1: full-lane, 2 elements/lane; writes h1[s] rows m, m+8 ----
        if (s < T_STEPS) {
            float e0[4], e1[4];
            #pragma unroll
            for (int g = 0; g < 4; ++g) {
                float s0 = __shfl_xor(accL1[g][0], 32, 64);
                float s1 = __shfl_xor(accL1[g][1], 32, 64);
                e0[g] = low ? s0 : accL1[g][2];   // low lanes take partner rows 8+4q..
                e1[g] = low ? s1 : accL1[g][3];
            }
            char* hw = (char*)smem + LDS_H1 + (s & 1) * 4096;
            #pragma unroll
            for (int e = 0; e < 2; ++e) {
                float gI = e ? e1[0] : e0[0];
                float gF = e ? e1[1] : e0[1];
                float gG = e ? e1[2] : e0[2];
                float gO = e ? e1[3] : e0[3];
                float si = sigf(gI), sf = sigf(gF), tg = tanhf_(gG), so = sigf(gO);
                c[2 + e] = sf * c[2 + e] + si * tg;
                float h = so * tanhf_(c[2 + e]);
                u16 hb = f2bf(h);
                *(u16*)(hw + cb + ((m0 + e) << 4))       = hb;
                *(u16*)(hw + cb + ((m0 + e + 8) << 4))   = hb;   // dup row m+8
            }
        }

        xcur = xnext;
        __syncthreads();
    }

    // epilogue: out[T-1] from h2[T-1] (written in slot T, visible after barrier)
    if (w == 7) {
        const char* h2r = smem + LDS_H2 + ((T_STEPS - 1) & 1) * 4096;
        v4f oa = {0.f, 0.f, 0.f, 0.f};
        #pragma unroll
        for (int kt = 0; kt < 4; ++kt) {
            v8s a = *(const v8s*)(h2r + (kt << 10) + l * 16);
            oa = MFMA_BF16(a, wlin[kt], oa, 0, 0, 0);
        }
        if (low && u < 4) {
            #pragma unroll
            for (int d = 0; d < 4; ++d)
                out[((long)(T_STEPS - 1) * BATCH + b0 + 4 * q + d) * 4 + u] = oa[d] + blin;
        }
    }
}

extern "C" void kernel_launch(void* const* d_in, const int* in_sizes, int n_in,
                              void* d_out, int out_size, void* d_ws, size_t ws_size,
                              hipStream_t stream) {
    const float* input = (const float*)d_in[0];
    // d_in[1] = future (unused, ==0)
    const float* W_ih1 = (const float*)d_in[2];
    const float* W_hh1 = (const float*)d_in[3];
    const float* b_ih1 = (const float*)d_in[4];
    const float* b_hh1 = (const float*)d_in[5];
    const float* W_ih2 = (const float*)d_in[6];
    const float* W_hh2 = (const float*)d_in[7];
    const float* b_ih2 = (const float*)d_in[8];
    const float* b_hh2 = (const float*)d_in[9];
    const float* W_lin = (const float*)d_in[10];
    const float* b_lin = (const float*)d_in[11];
    const float* h0    = (const float*)d_in[12];
    const float* c0    = (const float*)d_in[13];
    const float* h02   = (const float*)d_in[14];
    const float* c02   = (const float*)d_in[15];
    float* out = (float*)d_out;

    (void)hipFuncSetAttribute((const void*)lstm_seq_kernel,
                              hipFuncAttributeMaxDynamicSharedMemorySize, LDS_TOTAL);
    lstm_seq_kernel<<<BATCH / 8, 512, LDS_TOTAL, stream>>>(
        input, W_ih1, W_hh1, b_ih1, b_hh1, W_ih2, W_hh2, b_ih2, b_hh2,
        W_lin, b_lin, h0, c0, h02, c02, out);
}